// Round 15
// baseline (81.834 us; speedup 1.0000x reference)
//
#include <hip/hip_runtime.h>
#include <hip/hip_bf16.h>

typedef __bf16 bf16x8 __attribute__((ext_vector_type(8)));
typedef float  f32x4  __attribute__((ext_vector_type(4)));

static constexpr int NB = 8;
static constexpr int S  = 2048;
static constexpr int T  = 2048;
static constexpr int D  = 128;

// ws layout: wsrc[16384 rows][16 uint4], wtar[16384 rows][16 uint4]  (8 MB)
// Each row: 128 bf16 (normalized, mask-folded), slot q stored at (q ^ (row&7))
// == the exact LDS image the GEMM wants (global_load_lds copies linearly).

__device__ __forceinline__ void g2l(const uint4* g, uint4* l) {
    __builtin_amdgcn_global_load_lds((const __attribute__((address_space(1))) void*)g,
                                     (__attribute__((address_space(3))) void*)l, 16, 0, 0);
}

// ---------------- pass 1: normalize + mask-zero + bf16 + swizzled image ----------------
// XCD-local ownership: block p preps batch (p&7); with round-robin block->XCD
// dispatch, batch b's ws image is written and re-read on XCD b (dirty-local L2).
__global__ __launch_bounds__(512, 2)
void prep(const float* __restrict__ src, const float* __restrict__ tar,
          const int* __restrict__ ms, const int* __restrict__ mt,
          uint4* __restrict__ ws)
{
    const int tid   = threadIdx.x;
    const int p     = blockIdx.x;               // 0..255
    const int b     = p & 7;                    // batch == XCD (round-robin)
    const int chunk = p >> 3;                   // 0..31
    const int lr    = chunk * 128 + (tid >> 2); // 0..4095 batch-local row (src then tar)
    const int q     = tid & 3;                  // quarter-row
    const bool isT  = lr >= 2048;
    const int  r    = b * 2048 + (lr & 2047);   // global row within src/tar
    const float* pp = (isT ? tar : src) + (size_t)r * D + q * 32;
    const int   mk  = (isT ? mt : ms)[r];
    uint4*      wp  = ws + ((size_t)(isT ? NB * S : 0) + r) * 16;

    float4 v[8];
    float ss = 0.f;
    if (mk) {
        #pragma unroll
        for (int j = 0; j < 8; ++j) {
            v[j] = ((const float4*)pp)[j];
            ss += v[j].x * v[j].x + v[j].y * v[j].y + v[j].z * v[j].z + v[j].w * v[j].w;
        }
    } else {
        #pragma unroll
        for (int j = 0; j < 8; ++j) v[j] = float4{0.f, 0.f, 0.f, 0.f};
    }
    ss += __shfl_xor(ss, 1);                    // 4-lane group reduce (lanes of one row)
    ss += __shfl_xor(ss, 2);
    const float sc = mk ? (1.0f / fmaxf(sqrtf(ss), 1e-12f)) : 0.0f;

    #pragma unroll
    for (int i = 0; i < 4; ++i) {
        const float4 u0 = v[2 * i], u1 = v[2 * i + 1];
        bf16x8 t;
        t[0] = (__bf16)(u0.x * sc); t[1] = (__bf16)(u0.y * sc);
        t[2] = (__bf16)(u0.z * sc); t[3] = (__bf16)(u0.w * sc);
        t[4] = (__bf16)(u1.x * sc); t[5] = (__bf16)(u1.y * sc);
        t[6] = (__bf16)(u1.z * sc); t[7] = (__bf16)(u1.w * sc);
        wp[(q * 4 + i) ^ (r & 7)] = __builtin_bit_cast(uint4, t);
    }
}

// ---------------- pass 2: tiled GEMM, 48 KB LDS -> 3 blocks/CU ----------------
// R13 structure; ldsX quartered (16 KB) so three co-resident blocks keep the
// store pipe continuously fed while others are in stage/K-loop phases.
__global__ __launch_bounds__(512, 6)
void gemm(const uint4* __restrict__ ws, float* __restrict__ out)
{
    __shared__ uint4 ldsT[128 * 16];   // 32 KB  tar panel (A operand, 128 t-rows)
    __shared__ uint4 ldsX[32 * 32];    // 16 KB  f32 epilogue buffer (32 rows x 512B)

    const uint4* wsrc = ws;
    const uint4* wtar = ws + (size_t)NB * S * 16;

    const int blk = blockIdx.x;        // 0..1023 ; round-robin => b == XCD id
    const int b   = blk & 7;
    const int j   = blk >> 3;          // 0..127
    const int ts  = j >> 3;            // 0..15  source tile (128 rows)
    const int tp  = j & 7;             // 0..7   target pair (2 x 128 rows)

    const int tid  = threadIdx.x;
    const int lane = tid & 63;
    const int w    = tid >> 6;
    const int wt   = w & 1;            // 0..1  t-half (64 t-rows)
    const int wsp  = w >> 1;           // 0..3  s-quarter (32 s-rows)
    const int r16  = lane & 15;
    const int kg   = lane >> 4;        // 0..3
    const int swz  = r16 & 7;

    // ---- B operand (src rows) directly into registers, once per block ----
    bf16x8 bregs[2][4];
    #pragma unroll
    for (int n = 0; n < 2; ++n)
        #pragma unroll
        for (int ks = 0; ks < 4; ++ks) {
            const int R = b * S + ts * 128 + wsp * 32 + n * 16 + r16;
            bregs[n][ks] = __builtin_bit_cast(bf16x8, wsrc[(size_t)R * 16 + ((ks * 4 + kg) ^ swz)]);
        }

    // ---- stage first T panel ----
    const uint4* gt0 = wtar + ((size_t)(b * T + tp * 256)) * 16;
    #pragma unroll
    for (int i = 0; i < 4; ++i)
        g2l(gt0 + i * 512 + tid, &ldsT[i * 512 + w * 64]);
    asm volatile("s_waitcnt vmcnt(0)" ::: "memory");
    __builtin_amdgcn_s_barrier();
    __builtin_amdgcn_sched_barrier(0);

    f32x4 acc[4][2];

    #pragma unroll
    for (int tile = 0; tile < 2; ++tile) {
        #pragma unroll
        for (int m = 0; m < 4; ++m)
            #pragma unroll
            for (int n = 0; n < 2; ++n)
                acc[m][n] = f32x4{0.f, 0.f, 0.f, 0.f};

        #pragma unroll
        for (int ks = 0; ks < 4; ++ks) {          // K = 4 * 32
            bf16x8 at[4];
            #pragma unroll
            for (int m = 0; m < 4; ++m) {
                const int rl = wt * 64 + m * 16 + r16;
                at[m] = __builtin_bit_cast(bf16x8, ldsT[rl * 16 + ((ks * 4 + kg) ^ swz)]);
            }
            #pragma unroll
            for (int m = 0; m < 4; ++m)
                #pragma unroll
                for (int n = 0; n < 2; ++n)
                    acc[m][n] = __builtin_amdgcn_mfma_f32_16x16x32_bf16(at[m], bregs[n][ks], acc[m][n], 0, 0, 0);
        }

        if (tile == 0) {
            __syncthreads();                       // all waves done reading ldsT
            const uint4* gt1 = gt0 + 128 * 16;
            #pragma unroll
            for (int i = 0; i < 4; ++i)            // prefetch next tar panel (4 loads)
                g2l(gt1 + i * 512 + tid, &ldsT[i * 512 + w * 64]);
            __builtin_amdgcn_sched_barrier(0);     // pin: loads issued before stores
        }

        // ---- epilogue: acc -> ldsX (32-row quarters) -> 512B-contiguous wave stores ----
        const int ttc = tp * 2 + tile;
        #pragma unroll
        for (int h = 0; h < 4; ++h) {
            if (wsp == h) {                        // waves owning s-rows [h*32, h*32+32)
                #pragma unroll
                for (int m = 0; m < 4; ++m)
                    #pragma unroll
                    for (int n = 0; n < 2; ++n) {
                        const int lrow = n * 16 + r16;            // 0..31
                        const int col  = wt * 16 + m * 4 + kg;    // 0..31 (f32x4 slots)
                        const f32x4 a = acc[m][n];
                        f32x4 o;
                        o[0] = fmaxf(a[0], 0.f);
                        o[1] = fmaxf(a[1], 0.f);
                        o[2] = fmaxf(a[2], 0.f);
                        o[3] = fmaxf(a[3], 0.f);
                        ldsX[lrow * 32 + (col ^ (lrow & 31))] = __builtin_bit_cast(uint4, o);
                    }
            }
            asm volatile("s_waitcnt lgkmcnt(0)" ::: "memory");   // ds_writes visible
            __builtin_amdgcn_s_barrier();
            __builtin_amdgcn_sched_barrier(0);

            #pragma unroll
            for (int st = 0; st < 2; ++st) {       // 32 rows x 32 uint4 cooperative store
                const int flat = st * 512 + tid;   // 0..1023
                const int row  = flat >> 5;        // 0..31
                const int col  = flat & 31;
                const uint4 vv = ldsX[row * 32 + (col ^ (row & 31))];
                float* po = out + ((size_t)(b * S + ts * 128 + h * 32 + row)) * T
                                + (size_t)ttc * 128 + col * 4;
                *(f32x4*)po = __builtin_bit_cast(f32x4, vv);
            }

            // ldsX reads done before next quarter overwrites; stores stay in flight
            asm volatile("s_waitcnt lgkmcnt(0)" ::: "memory");
            if (tile == 0 && h == 3)
                asm volatile("s_waitcnt vmcnt(8)" ::: "memory");  // retire the 4 g2l (8 younger stores ok)
            __builtin_amdgcn_s_barrier();
            __builtin_amdgcn_sched_barrier(0);
        }
    }
}

extern "C" void kernel_launch(void* const* d_in, const int* in_sizes, int n_in,
                              void* d_out, int out_size, void* d_ws, size_t ws_size,
                              hipStream_t stream) {
    const float* src    = (const float*)d_in[0];
    const float* tar    = (const float*)d_in[1];
    const int*   mask_s = (const int*)d_in[2];
    const int*   mask_t = (const int*)d_in[3];
    float*       out    = (float*)d_out;
    uint4*       ws     = (uint4*)d_ws;

    hipLaunchKernelGGL(prep, dim3(256), dim3(512), 0, stream, src, tar, mask_s, mask_t, ws);
    hipLaunchKernelGGL(gemm, dim3(1024), dim3(512), 0, stream, ws, out);
}

// Round 16
// 35.065 us; speedup vs baseline: 2.3338x; 2.3338x over previous
//
#include <hip/hip_runtime.h>
#include <hip/hip_bf16.h>

typedef __bf16 bf16x8 __attribute__((ext_vector_type(8)));
typedef float  f32x4  __attribute__((ext_vector_type(4)));

static constexpr int NB = 8;
static constexpr int S  = 2048;
static constexpr int T  = 2048;
static constexpr int D  = 128;

// ws layout: wsrc[16384 rows][16 uint4], wtar[16384 rows][16 uint4]  (8 MB)
// Each row: 128 bf16 (normalized, mask-folded), slot q stored at (q ^ (row&7))
// == the exact LDS image the GEMM wants (global_load_lds copies linearly).

__device__ __forceinline__ void g2l(const uint4* g, uint4* l) {
    __builtin_amdgcn_global_load_lds((const __attribute__((address_space(1))) void*)g,
                                     (__attribute__((address_space(3))) void*)l, 16, 0, 0);
}

// ---------------- pass 1: normalize + mask-zero + bf16 + swizzled image ----------------
// XCD-local ownership: block p preps batch (p&7); with round-robin block->XCD
// dispatch, batch b's ws image is written and re-read on XCD b (dirty-local L2).
__global__ __launch_bounds__(512, 2)
void prep(const float* __restrict__ src, const float* __restrict__ tar,
          const int* __restrict__ ms, const int* __restrict__ mt,
          uint4* __restrict__ ws)
{
    const int tid   = threadIdx.x;
    const int p     = blockIdx.x;               // 0..255
    const int b     = p & 7;                    // batch == XCD (round-robin)
    const int chunk = p >> 3;                   // 0..31
    const int lr    = chunk * 128 + (tid >> 2); // 0..4095 batch-local row (src then tar)
    const int q     = tid & 3;                  // quarter-row
    const bool isT  = lr >= 2048;
    const int  r    = b * 2048 + (lr & 2047);   // global row within src/tar
    const float* pp = (isT ? tar : src) + (size_t)r * D + q * 32;
    const int   mk  = (isT ? mt : ms)[r];
    uint4*      wp  = ws + ((size_t)(isT ? NB * S : 0) + r) * 16;

    float4 v[8];
    float ss = 0.f;
    if (mk) {
        #pragma unroll
        for (int j = 0; j < 8; ++j) {
            v[j] = ((const float4*)pp)[j];
            ss += v[j].x * v[j].x + v[j].y * v[j].y + v[j].z * v[j].z + v[j].w * v[j].w;
        }
    } else {
        #pragma unroll
        for (int j = 0; j < 8; ++j) v[j] = float4{0.f, 0.f, 0.f, 0.f};
    }
    ss += __shfl_xor(ss, 1);                    // 4-lane group reduce (lanes of one row)
    ss += __shfl_xor(ss, 2);
    const float sc = mk ? (1.0f / fmaxf(sqrtf(ss), 1e-12f)) : 0.0f;

    #pragma unroll
    for (int i = 0; i < 4; ++i) {
        const float4 u0 = v[2 * i], u1 = v[2 * i + 1];
        bf16x8 t;
        t[0] = (__bf16)(u0.x * sc); t[1] = (__bf16)(u0.y * sc);
        t[2] = (__bf16)(u0.z * sc); t[3] = (__bf16)(u0.w * sc);
        t[4] = (__bf16)(u1.x * sc); t[5] = (__bf16)(u1.y * sc);
        t[6] = (__bf16)(u1.z * sc); t[7] = (__bf16)(u1.w * sc);
        wp[(q * 4 + i) ^ (r & 7)] = __builtin_bit_cast(uint4, t);
    }
}

// ---------------- pass 2: tiled GEMM, 48 KB LDS -> 3 blocks/CU (no VGPR squeeze) ----
// launch_bounds(512,4): allocator targets <=128 VGPR (natural ~64, no spill);
// occupancy is then LDS-limited at 48 KB -> 3 co-resident blocks/CU whose
// staggered phases keep the store pipe continuously fed.
__global__ __launch_bounds__(512, 4)
void gemm(const uint4* __restrict__ ws, float* __restrict__ out)
{
    __shared__ uint4 ldsT[128 * 16];   // 32 KB  tar panel (A operand, 128 t-rows)
    __shared__ uint4 ldsX[32 * 32];    // 16 KB  f32 epilogue buffer (32 rows x 512B)

    const uint4* wsrc = ws;
    const uint4* wtar = ws + (size_t)NB * S * 16;

    const int blk = blockIdx.x;        // 0..1023 ; round-robin => b == XCD id
    const int b   = blk & 7;
    const int j   = blk >> 3;          // 0..127
    const int ts  = j >> 3;            // 0..15  source tile (128 rows)
    const int tp  = j & 7;             // 0..7   target pair (2 x 128 rows)

    const int tid  = threadIdx.x;
    const int lane = tid & 63;
    const int w    = tid >> 6;
    const int wt   = w & 1;            // 0..1  t-half (64 t-rows)
    const int wsp  = w >> 1;           // 0..3  s-quarter (32 s-rows)
    const int r16  = lane & 15;
    const int kg   = lane >> 4;        // 0..3
    const int swz  = r16 & 7;

    // ---- B operand (src rows) directly into registers, once per block ----
    bf16x8 bregs[2][4];
    #pragma unroll
    for (int n = 0; n < 2; ++n)
        #pragma unroll
        for (int ks = 0; ks < 4; ++ks) {
            const int R = b * S + ts * 128 + wsp * 32 + n * 16 + r16;
            bregs[n][ks] = __builtin_bit_cast(bf16x8, wsrc[(size_t)R * 16 + ((ks * 4 + kg) ^ swz)]);
        }

    // ---- stage first T panel ----
    const uint4* gt0 = wtar + ((size_t)(b * T + tp * 256)) * 16;
    #pragma unroll
    for (int i = 0; i < 4; ++i)
        g2l(gt0 + i * 512 + tid, &ldsT[i * 512 + w * 64]);
    asm volatile("s_waitcnt vmcnt(0)" ::: "memory");
    __builtin_amdgcn_s_barrier();
    __builtin_amdgcn_sched_barrier(0);

    f32x4 acc[4][2];

    #pragma unroll
    for (int tile = 0; tile < 2; ++tile) {
        #pragma unroll
        for (int m = 0; m < 4; ++m)
            #pragma unroll
            for (int n = 0; n < 2; ++n)
                acc[m][n] = f32x4{0.f, 0.f, 0.f, 0.f};

        #pragma unroll
        for (int ks = 0; ks < 4; ++ks) {          // K = 4 * 32
            bf16x8 at[4];
            #pragma unroll
            for (int m = 0; m < 4; ++m) {
                const int rl = wt * 64 + m * 16 + r16;
                at[m] = __builtin_bit_cast(bf16x8, ldsT[rl * 16 + ((ks * 4 + kg) ^ swz)]);
            }
            #pragma unroll
            for (int m = 0; m < 4; ++m)
                #pragma unroll
                for (int n = 0; n < 2; ++n)
                    acc[m][n] = __builtin_amdgcn_mfma_f32_16x16x32_bf16(at[m], bregs[n][ks], acc[m][n], 0, 0, 0);
        }

        if (tile == 0) {
            __syncthreads();                       // all waves done reading ldsT
            const uint4* gt1 = gt0 + 128 * 16;
            #pragma unroll
            for (int i = 0; i < 4; ++i)            // prefetch next tar panel (4 loads)
                g2l(gt1 + i * 512 + tid, &ldsT[i * 512 + w * 64]);
            __builtin_amdgcn_sched_barrier(0);     // pin: loads issued before stores
        }

        // ---- epilogue: acc -> ldsX (32-row quarters) -> 512B-contiguous wave stores ----
        const int ttc = tp * 2 + tile;
        #pragma unroll
        for (int h = 0; h < 4; ++h) {
            if (wsp == h) {                        // waves owning s-rows [h*32, h*32+32)
                #pragma unroll
                for (int m = 0; m < 4; ++m)
                    #pragma unroll
                    for (int n = 0; n < 2; ++n) {
                        const int lrow = n * 16 + r16;            // 0..31
                        const int col  = wt * 16 + m * 4 + kg;    // 0..31 (f32x4 slots)
                        const f32x4 a = acc[m][n];
                        f32x4 o;
                        o[0] = fmaxf(a[0], 0.f);
                        o[1] = fmaxf(a[1], 0.f);
                        o[2] = fmaxf(a[2], 0.f);
                        o[3] = fmaxf(a[3], 0.f);
                        ldsX[lrow * 32 + (col ^ (lrow & 31))] = __builtin_bit_cast(uint4, o);
                    }
            }
            asm volatile("s_waitcnt lgkmcnt(0)" ::: "memory");   // ds_writes visible
            __builtin_amdgcn_s_barrier();
            __builtin_amdgcn_sched_barrier(0);

            #pragma unroll
            for (int st = 0; st < 2; ++st) {       // 32 rows x 32 uint4 cooperative store
                const int flat = st * 512 + tid;   // 0..1023
                const int row  = flat >> 5;        // 0..31
                const int col  = flat & 31;
                const uint4 vv = ldsX[row * 32 + (col ^ (row & 31))];
                float* po = out + ((size_t)(b * S + ts * 128 + h * 32 + row)) * T
                                + (size_t)ttc * 128 + col * 4;
                *(f32x4*)po = __builtin_bit_cast(f32x4, vv);
            }

            // ldsX reads done before next quarter overwrites; stores stay in flight
            asm volatile("s_waitcnt lgkmcnt(0)" ::: "memory");
            if (tile == 0 && h == 3)
                asm volatile("s_waitcnt vmcnt(8)" ::: "memory");  // retire the 4 g2l (8 younger stores ok)
            __builtin_amdgcn_s_barrier();
            __builtin_amdgcn_sched_barrier(0);
        }
    }
}

extern "C" void kernel_launch(void* const* d_in, const int* in_sizes, int n_in,
                              void* d_out, int out_size, void* d_ws, size_t ws_size,
                              hipStream_t stream) {
    const float* src    = (const float*)d_in[0];
    const float* tar    = (const float*)d_in[1];
    const int*   mask_s = (const int*)d_in[2];
    const int*   mask_t = (const int*)d_in[3];
    float*       out    = (float*)d_out;
    uint4*       ws     = (uint4*)d_ws;

    hipLaunchKernelGGL(prep, dim3(256), dim3(512), 0, stream, src, tar, mask_s, mask_t, ws);
    hipLaunchKernelGGL(gemm, dim3(1024), dim3(512), 0, stream, ws, out);
}